// Round 1
// baseline (9896.318 us; speedup 1.0000x reference)
//
#include <hip/hip_runtime.h>
#include <cstdint>
#include <cstddef>

#define F_CH 76
#define T_LEN 4096
#define B_TOT 64
#define C_CLS 15
#define TT 128
#define NSTEP 8

// ---------------- transpose: x [B,T,F] -> h [Bc,F,T] ----------------
__global__ __launch_bounds__(256) void transpose_kernel(
    const float* __restrict__ x, float* __restrict__ h, int b0)
{
    __shared__ float tile[32][F_CH + 1];
    int bl = blockIdx.y;
    int t0 = blockIdx.x * 32;
    const float* xb = x + ((size_t)(b0 + bl) * T_LEN) * F_CH;
    // contiguous read of 32 rows x 76 floats
    for (int idx = threadIdx.x; idx < 32 * F_CH; idx += 256) {
        int tt = idx / F_CH, f = idx - tt * F_CH;
        tile[tt][f] = xb[(size_t)t0 * F_CH + idx];
    }
    __syncthreads();
    float* hb = h + (size_t)bl * F_CH * T_LEN;
    for (int odx = threadIdx.x; odx < 32 * F_CH; odx += 256) {
        int f = odx >> 5, tt = odx & 31;
        hb[(size_t)f * T_LEN + t0 + tt] = tile[tt][f];
    }
}

// ------------- one ODE-function eval + RK4 stage bookkeeping -------------
// mode 0 (k1): hnext = h + dt/6*k ; snew = h + dt/2*k   (conv input IS h)
// mode 1 (k2): hnext += dt/3*k   ; snew = h + dt/2*k
// mode 2 (k3): hnext += dt/3*k   ; snew = h + dt*k
// mode 3 (k4): hnext += dt/6*k
__global__ __launch_bounds__(256) void conv_eval_kernel(
    const float* __restrict__ s, const float* __restrict__ h,
    float* __restrict__ hnext, float* __restrict__ snew,
    const float* __restrict__ cw, const float* __restrict__ cb, int mode)
{
    __shared__ float tile[F_CH][TT + 2];
    int b  = blockIdx.y;
    int t0 = blockIdx.x * TT;
    const float* sb = s + (size_t)b * F_CH * T_LEN;
    for (int idx = threadIdx.x; idx < F_CH * (TT + 2); idx += 256) {
        int c  = idx / (TT + 2);
        int tt = idx - c * (TT + 2);
        int t  = t0 + tt - 1;
        tile[c][tt] = (t >= 0 && t < T_LEN) ? sb[(size_t)c * T_LEN + t] : 0.0f;
    }
    __syncthreads();

    int tt = threadIdx.x & (TT - 1);
    // wave-uniform c_out base: force SGPR so weight loads become s_load
    int c0 = __builtin_amdgcn_readfirstlane((threadIdx.x >> 7) * 38);

    float acc[38];
#pragma unroll
    for (int j = 0; j < 38; ++j) acc[j] = 0.0f;

    for (int ci = 0; ci < F_CH; ++ci) {
        float sm = tile[ci][tt];
        float sc = tile[ci][tt + 1];
        float sp = tile[ci][tt + 2];
        const float* w = cw + (size_t)(c0 * F_CH + ci) * 3;
#pragma unroll
        for (int j = 0; j < 38; ++j) {
            acc[j] = fmaf(w[(size_t)j * F_CH * 3 + 0], sm, acc[j]);
            acc[j] = fmaf(w[(size_t)j * F_CH * 3 + 1], sc, acc[j]);
            acc[j] = fmaf(w[(size_t)j * F_CH * 3 + 2], sp, acc[j]);
        }
    }

    const float dt = 1.0f / 8.0f;
    size_t base = (size_t)b * F_CH * T_LEN + (size_t)t0 + tt;
#pragma unroll
    for (int j = 0; j < 38; ++j) {
        int c = c0 + j;
        float k = tanhf(acc[j] + cb[c]);
        size_t off = base + (size_t)c * T_LEN;
        if (mode == 0) {
            float hv = tile[c][tt + 1];          // conv input == h
            hnext[off] = hv + (dt / 6.0f) * k;
            snew[off]  = hv + 0.5f * dt * k;
        } else if (mode == 3) {
            hnext[off] += (dt / 6.0f) * k;
        } else {
            float hv = h[off];
            hnext[off] += (dt / 3.0f) * k;
            snew[off]  = hv + ((mode == 2) ? dt : 0.5f * dt) * k;
        }
    }
}

// ------------- final linear: out[b,t,c] = sum_f h[b,f,t]*fw[c,f] + fb[c] -------------
__global__ __launch_bounds__(256) void final_kernel(
    const float* __restrict__ h, const float* __restrict__ fw,
    const float* __restrict__ fb, float* __restrict__ out, int b0)
{
    int bl = blockIdx.y;
    int t  = blockIdx.x * 256 + threadIdx.x;
    const float* hb = h + (size_t)bl * F_CH * T_LEN;
    float acc[C_CLS];
#pragma unroll
    for (int c = 0; c < C_CLS; ++c) acc[c] = fb[c];
    for (int f = 0; f < F_CH; ++f) {
        float hv = hb[(size_t)f * T_LEN + t];
#pragma unroll
        for (int c = 0; c < C_CLS; ++c) acc[c] = fmaf(fw[c * F_CH + f], hv, acc[c]);
    }
    float* ob = out + ((size_t)(b0 + bl) * T_LEN + t) * C_CLS;
#pragma unroll
    for (int c = 0; c < C_CLS; ++c) ob[c] = acc[c];
}

extern "C" void kernel_launch(void* const* d_in, const int* in_sizes, int n_in,
                              void* d_out, int out_size, void* d_ws, size_t ws_size,
                              hipStream_t stream)
{
    const float* x  = (const float*)d_in[0];
    const float* cw = (const float*)d_in[1];
    const float* cb = (const float*)d_in[2];
    const float* fw = (const float*)d_in[3];
    const float* fb = (const float*)d_in[4];
    float* out = (float*)d_out;

    const size_t FT = (size_t)F_CH * T_LEN;          // floats per batch plane
    const size_t perBatchBytes = 4 * FT * sizeof(float); // 4 state buffers
    int Bc = (int)(ws_size / perBatchBytes);
    if (Bc > B_TOT) Bc = B_TOT;
    if (Bc < 1) Bc = 1;

    float* H0 = (float*)d_ws;
    float* H1 = H0 + (size_t)Bc * FT;
    float* S0 = H1 + (size_t)Bc * FT;
    float* S1 = S0 + (size_t)Bc * FT;

    for (int b0 = 0; b0 < B_TOT; b0 += Bc) {
        int bc = (B_TOT - b0 < Bc) ? (B_TOT - b0) : Bc;

        dim3 gT(T_LEN / 32, bc);
        transpose_kernel<<<gT, 256, 0, stream>>>(x, H0, b0);

        float* hcur = H0;
        float* hnxt = H1;
        dim3 gC(T_LEN / TT, bc);
        for (int st = 0; st < NSTEP; ++st) {
            conv_eval_kernel<<<gC, 256, 0, stream>>>(hcur, hcur, hnxt, S0, cw, cb, 0);
            conv_eval_kernel<<<gC, 256, 0, stream>>>(S0, hcur, hnxt, S1, cw, cb, 1);
            conv_eval_kernel<<<gC, 256, 0, stream>>>(S1, hcur, hnxt, S0, cw, cb, 2);
            conv_eval_kernel<<<gC, 256, 0, stream>>>(S0, hcur, hnxt, S0, cw, cb, 3);
            float* tmp = hcur; hcur = hnxt; hnxt = tmp;
        }

        dim3 gF(T_LEN / 256, bc);
        final_kernel<<<gF, 256, 0, stream>>>(hcur, fw, fb, out, b0);
    }
}

// Round 2
// 6328.902 us; speedup vs baseline: 1.5637x; 1.5637x over previous
//
#include <hip/hip_runtime.h>
#include <cstdint>
#include <cstddef>

#define F_CH 76
#define T_LEN 4096
#define B_TOT 64
#define C_CLS 15
#define NSTEP 8
#define TTILE 256          // t-points per block (64 lanes x 4)
#define JCH 19             // output channels per wave (4 waves x 19 = 76)
#define WPAD 60            // padded weight row length (57 used)
#define WP_FLOATS (4 * F_CH * WPAD)

// ---------------- transpose: x [B,T,F] -> h [Bc,F,T] ----------------
__global__ __launch_bounds__(256) void transpose_kernel(
    const float* __restrict__ x, float* __restrict__ h, int b0)
{
    __shared__ float tile[32][F_CH + 1];
    int bl = blockIdx.y;
    int t0 = blockIdx.x * 32;
    const float* xb = x + ((size_t)(b0 + bl) * T_LEN) * F_CH;
    for (int idx = threadIdx.x; idx < 32 * F_CH; idx += 256) {
        int tt = idx / F_CH, f = idx - tt * F_CH;
        tile[tt][f] = xb[(size_t)t0 * F_CH + idx];
    }
    __syncthreads();
    float* hb = h + (size_t)bl * F_CH * T_LEN;
    for (int odx = threadIdx.x; odx < 32 * F_CH; odx += 256) {
        int f = odx >> 5, tt = odx & 31;
        hb[(size_t)f * T_LEN + t0 + tt] = tile[tt][f];
    }
}

// ------- weight repack: wp[g][ci][j*3+k] = cw[g*19+j][ci][k], rows padded to 60 -------
__global__ void wprep_kernel(const float* __restrict__ cw, float* __restrict__ wp)
{
    int idx = blockIdx.x * 256 + threadIdx.x;
    if (idx >= WP_FLOATS) return;
    int row = idx / WPAD, rem = idx - row * WPAD;
    int g = row / F_CH, ci = row - g * F_CH;
    float v = 0.0f;
    if (rem < JCH * 3) {
        int j = rem / 3, k = rem - j * 3;
        int c = g * JCH + j;
        v = cw[((size_t)c * F_CH + ci) * 3 + k];
    }
    wp[idx] = v;
}

// ------------- one ODE-function eval + RK4 stage bookkeeping -------------
// MODE 0 (k1): hnext = h + dt/6*k ; snew = h + dt/2*k   (s == h)
// MODE 1 (k2): hnext += dt/3*k   ; snew = h + dt/2*k
// MODE 2 (k3): hnext += dt/3*k   ; snew = h + dt*k
// MODE 3 (k4): hnext += dt/6*k
template<int MODE>
__global__ __launch_bounds__(256, 4) void conv_eval_kernel(
    const float* __restrict__ s, const float* __restrict__ h,
    float* __restrict__ hnext, float* __restrict__ snew,
    const float* __restrict__ wp, const float* __restrict__ cb)
{
    const int b    = blockIdx.y;
    const int lane = threadIdx.x & 63;
    const int g    = __builtin_amdgcn_readfirstlane(threadIdx.x >> 6);
    const int t0   = blockIdx.x * TTILE + lane * 4;

    const float* sb = s + (size_t)b * F_CH * T_LEN + t0;
    const float* wg = wp + (size_t)g * F_CH * WPAD;

    float acc[JCH][4];
#pragma unroll
    for (int j = 0; j < JCH; ++j)
#pragma unroll
        for (int u = 0; u < 4; ++u) acc[j][u] = 0.0f;

    const bool left  = (t0 == 0);
    const bool right = (t0 + 4 >= T_LEN);
    const int  moff  = left ? 0 : -1;
    const int  poff  = right ? 3 : 4;

#pragma unroll 1
    for (int ci = 0; ci < F_CH; ++ci) {
        const float* srow = sb + (size_t)ci * T_LEN;
        const float4 v = *(const float4*)srow;
        float m = srow[moff]; if (left)  m = 0.0f;
        float p = srow[poff]; if (right) p = 0.0f;
        const float* w = wg + ci * WPAD;
#pragma unroll
        for (int j = 0; j < JCH; ++j) {
            const float w0 = w[j * 3 + 0], w1 = w[j * 3 + 1], w2 = w[j * 3 + 2];
            acc[j][0] = fmaf(w0, m,   fmaf(w1, v.x, fmaf(w2, v.y, acc[j][0])));
            acc[j][1] = fmaf(w0, v.x, fmaf(w1, v.y, fmaf(w2, v.z, acc[j][1])));
            acc[j][2] = fmaf(w0, v.y, fmaf(w1, v.z, fmaf(w2, v.w, acc[j][2])));
            acc[j][3] = fmaf(w0, v.z, fmaf(w1, v.w, fmaf(w2, p,   acc[j][3])));
        }
    }

    const float dt = 0.125f;
    const size_t base = (size_t)b * F_CH * T_LEN + t0;
#pragma unroll
    for (int j = 0; j < JCH; ++j) {
        const int c = g * JCH + j;
        const size_t off = base + (size_t)c * T_LEN;
        const float bias = cb[c];
        float4 k;
        k.x = tanhf(acc[j][0] + bias);
        k.y = tanhf(acc[j][1] + bias);
        k.z = tanhf(acc[j][2] + bias);
        k.w = tanhf(acc[j][3] + bias);
        if (MODE == 0) {
            float4 hv = *(const float4*)(h + off);
            float4 hn, sn;
            hn.x = hv.x + (dt / 6.0f) * k.x;  hn.y = hv.y + (dt / 6.0f) * k.y;
            hn.z = hv.z + (dt / 6.0f) * k.z;  hn.w = hv.w + (dt / 6.0f) * k.w;
            sn.x = hv.x + 0.5f * dt * k.x;    sn.y = hv.y + 0.5f * dt * k.y;
            sn.z = hv.z + 0.5f * dt * k.z;    sn.w = hv.w + 0.5f * dt * k.w;
            *(float4*)(hnext + off) = hn;
            *(float4*)(snew + off)  = sn;
        } else if (MODE == 3) {
            float4 hn = *(const float4*)(hnext + off);
            hn.x += (dt / 6.0f) * k.x;  hn.y += (dt / 6.0f) * k.y;
            hn.z += (dt / 6.0f) * k.z;  hn.w += (dt / 6.0f) * k.w;
            *(float4*)(hnext + off) = hn;
        } else {
            const float sf = (MODE == 2) ? dt : 0.5f * dt;
            float4 hv = *(const float4*)(h + off);
            float4 hn = *(const float4*)(hnext + off);
            hn.x += (dt / 3.0f) * k.x;  hn.y += (dt / 3.0f) * k.y;
            hn.z += (dt / 3.0f) * k.z;  hn.w += (dt / 3.0f) * k.w;
            *(float4*)(hnext + off) = hn;
            float4 sn;
            sn.x = hv.x + sf * k.x;  sn.y = hv.y + sf * k.y;
            sn.z = hv.z + sf * k.z;  sn.w = hv.w + sf * k.w;
            *(float4*)(snew + off) = sn;
        }
    }
}

// ------------- final linear -------------
__global__ __launch_bounds__(256) void final_kernel(
    const float* __restrict__ h, const float* __restrict__ fw,
    const float* __restrict__ fb, float* __restrict__ out, int b0)
{
    int bl = blockIdx.y;
    int t  = blockIdx.x * 256 + threadIdx.x;
    const float* hb = h + (size_t)bl * F_CH * T_LEN;
    float acc[C_CLS];
#pragma unroll
    for (int c = 0; c < C_CLS; ++c) acc[c] = fb[c];
    for (int f = 0; f < F_CH; ++f) {
        float hv = hb[(size_t)f * T_LEN + t];
#pragma unroll
        for (int c = 0; c < C_CLS; ++c) acc[c] = fmaf(fw[c * F_CH + f], hv, acc[c]);
    }
    float* ob = out + ((size_t)(b0 + bl) * T_LEN + t) * C_CLS;
#pragma unroll
    for (int c = 0; c < C_CLS; ++c) ob[c] = acc[c];
}

extern "C" void kernel_launch(void* const* d_in, const int* in_sizes, int n_in,
                              void* d_out, int out_size, void* d_ws, size_t ws_size,
                              hipStream_t stream)
{
    const float* x  = (const float*)d_in[0];
    const float* cw = (const float*)d_in[1];
    const float* cb = (const float*)d_in[2];
    const float* fw = (const float*)d_in[3];
    const float* fb = (const float*)d_in[4];
    float* out = (float*)d_out;

    const size_t FT = (size_t)F_CH * T_LEN;
    float* WP = (float*)d_ws;
    const size_t wpFloats = ((WP_FLOATS + 79) / 80) * 80;   // pad, keep 16B align
    float* planes = WP + wpFloats;

    size_t planeBytes = 4 * FT * sizeof(float);
    size_t avail = ws_size - wpFloats * sizeof(float);
    int Bc = (int)(avail / planeBytes);
    if (Bc > B_TOT) Bc = B_TOT;
    if (Bc < 1) Bc = 1;

    float* H0 = planes;
    float* H1 = H0 + (size_t)Bc * FT;
    float* S0 = H1 + (size_t)Bc * FT;
    float* S1 = S0 + (size_t)Bc * FT;

    wprep_kernel<<<(WP_FLOATS + 255) / 256, 256, 0, stream>>>(cw, WP);

    for (int b0 = 0; b0 < B_TOT; b0 += Bc) {
        int bc = (B_TOT - b0 < Bc) ? (B_TOT - b0) : Bc;

        dim3 gT(T_LEN / 32, bc);
        transpose_kernel<<<gT, 256, 0, stream>>>(x, H0, b0);

        float* hcur = H0;
        float* hnxt = H1;
        dim3 gC(T_LEN / TTILE, bc);
        for (int st = 0; st < NSTEP; ++st) {
            conv_eval_kernel<0><<<gC, 256, 0, stream>>>(hcur, hcur, hnxt, S0, WP, cb);
            conv_eval_kernel<1><<<gC, 256, 0, stream>>>(S0, hcur, hnxt, S1, WP, cb);
            conv_eval_kernel<2><<<gC, 256, 0, stream>>>(S1, hcur, hnxt, S0, WP, cb);
            conv_eval_kernel<3><<<gC, 256, 0, stream>>>(S0, hcur, hnxt, S0, WP, cb);
            float* tmp = hcur; hcur = hnxt; hnxt = tmp;
        }

        dim3 gF(T_LEN / 256, bc);
        final_kernel<<<gF, 256, 0, stream>>>(hcur, fw, fb, out, b0);
    }
}

// Round 4
// 3612.592 us; speedup vs baseline: 2.7394x; 1.7519x over previous
//
#include <hip/hip_runtime.h>
#include <cstdint>
#include <cstddef>

#define F_CH 76
#define T_LEN 4096
#define B_TOT 64
#define C_CLS 15
#define NSTEP 8

// ---- rk4 fused-step kernel geometry ----
#define W_OUT  248           // output t per block (halo 4 each side)
#define HALO   4
#define NBT    17            // ceil(4096/248)
#define KPAD   80            // ci padded to 80 (5 k-blocks of 16)
#define NKB    5
#define SSTR   88            // LDS row stride in bf16
#define SROWS  258           // 256 compute rows + 2 halo
#define TPB    384           // 6 waves

typedef __attribute__((ext_vector_type(8)))  __bf16 bf16x8;
typedef __attribute__((ext_vector_type(4)))  __bf16 bf16x4;
typedef __attribute__((ext_vector_type(16))) float  f32x16;
typedef __attribute__((ext_vector_type(4)))  float  f32x4;

// ---------------- transpose: x [B,T,F] -> h [Bc,F,T] ----------------
__global__ __launch_bounds__(256) void transpose_kernel(
    const float* __restrict__ x, float* __restrict__ h, int b0)
{
    __shared__ float tile[32][F_CH + 1];
    int bl = blockIdx.y;
    int t0 = blockIdx.x * 32;
    const float* xb = x + ((size_t)(b0 + bl) * T_LEN) * F_CH;
    for (int idx = threadIdx.x; idx < 32 * F_CH; idx += 256) {
        int tt = idx / F_CH, f = idx - tt * F_CH;
        tile[tt][f] = xb[(size_t)t0 * F_CH + idx];
    }
    __syncthreads();
    float* hb = h + (size_t)bl * F_CH * T_LEN;
    for (int odx = threadIdx.x; odx < 32 * F_CH; odx += 256) {
        int f = odx >> 5, tt = odx & 31;
        hb[(size_t)f * T_LEN + t0 + tt] = tile[tt][f];
    }
}

// ---- weight prep: cw [76][76][3] f32 -> wpb [3][96][SSTR] bf16 (zero-padded) ----
__global__ __launch_bounds__(256) void wprep_kernel(
    const float* __restrict__ cw, __bf16* __restrict__ wpb)
{
    int idx = blockIdx.x * 256 + threadIdx.x;
    if (idx >= 3 * 96 * SSTR) return;
    int tap = idx / (96 * SSTR);
    int rem = idx - tap * 96 * SSTR;
    int c = rem / SSTR, ci = rem - c * SSTR;
    float v = 0.0f;
    if (c < F_CH && ci < F_CH) v = cw[((size_t)c * F_CH + ci) * 3 + tap];
    wpb[idx] = (__bf16)v;
}

// ---------------- fused RK4 step: hout = h + dt/6 (k1+2k2+2k3+k4) ----------------
__global__ __launch_bounds__(TPB, 2) void rk4_step_kernel(
    const float* __restrict__ hin, float* __restrict__ hout,
    const __bf16* __restrict__ wpb, const float* __restrict__ cb)
{
    __shared__ __bf16 s_lds[SROWS][SSTR];
    __shared__ __bf16 w_lds[3][96][SSTR];
    __shared__ float  cb_lds[96];

    const int b    = blockIdx.y;
    const int T0   = blockIdx.x * W_OUT;
    const int tid  = threadIdx.x;
    const int lane = tid & 63;
    const int wv   = tid >> 6;          // 0..5
    const int l31  = lane & 31;
    const int l5   = lane >> 5;         // 0..1
    const int ct   = wv >> 1;           // c-tile 0..2 (rows ct*32..+31)
    const int tth  = wv & 1;            // t-half

    // ---- stage weights & bias to LDS; zero s_lds ----
    {
        const uint32_t* src = (const uint32_t*)wpb;
        uint32_t* dst = (uint32_t*)&w_lds[0][0][0];
        const int n = 3 * 96 * SSTR / 2;
        for (int i = tid; i < n; i += TPB) dst[i] = src[i];
        for (int i = tid; i < 96; i += TPB) cb_lds[i] = (i < F_CH) ? cb[i] : 0.0f;
        uint32_t* sz = (uint32_t*)&s_lds[0][0];
        for (int i = tid; i < SROWS * SSTR / 2; i += TPB) sz[i] = 0u;
    }

    // ---- load h (f32) into registers; init hn accumulator ----
    float h_reg[4][16], hn[4][16];
    int  rbase[4];
    bool tok[4];
    const float* hb = hin + (size_t)b * F_CH * T_LEN;
    #pragma unroll
    for (int tt = 0; tt < 4; ++tt) {
        int ttg = tth * 4 + tt;
        rbase[tt] = ttg * 32 + l31;
        int t = T0 - HALO + rbase[tt];
        tok[tt] = (t >= 0 && t < T_LEN);
        #pragma unroll
        for (int q = 0; q < 4; ++q) {
            int c0 = ct * 32 + l5 * 4 + q * 8;
            #pragma unroll
            for (int j = 0; j < 4; ++j) {
                float v = 0.0f;
                int c = c0 + j;
                if (tok[tt] && c < F_CH) v = hb[(size_t)c * T_LEN + t];
                h_reg[tt][q * 4 + j] = v;
                hn[tt][q * 4 + j]    = v;
            }
        }
    }
    __syncthreads();   // staging + zeroing complete

    // ---- write s1 = bf16(h)  (guard: quad must fit inside SSTR row) ----
    #pragma unroll
    for (int tt = 0; tt < 4; ++tt) {
        #pragma unroll
        for (int q = 0; q < 4; ++q) {
            int c0 = ct * 32 + l5 * 4 + q * 8;
            if (c0 + 4 <= SSTR) {
                bf16x4 p;
                #pragma unroll
                for (int j = 0; j < 4; ++j) p[j] = (__bf16)h_reg[tt][q * 4 + j];
                *(bf16x4*)&s_lds[rbase[tt] + 1][c0] = p;
            }
        }
    }
    __syncthreads();

    // ---- cache A fragments (taps 0,1) for our c-tile; tap 2 read per use ----
    bf16x8 afr[2][NKB];
    #pragma unroll
    for (int tap = 0; tap < 2; ++tap)
        #pragma unroll
        for (int kb = 0; kb < NKB; ++kb)
            afr[tap][kb] = *(const bf16x8*)&w_lds[tap][ct * 32 + l31][kb * 16 + l5 * 8];

    const float dt = 0.125f;
    bf16x4 spack[4][4];

    #pragma unroll 1
    for (int e = 0; e < 4; ++e) {
        const float we = (e == 0 || e == 3) ? dt / 6.0f : dt / 3.0f;
        const float al = (e == 2) ? dt : 0.5f * dt;
        #pragma unroll
        for (int tt = 0; tt < 4; ++tt) {
            f32x16 acc = {};
            #pragma unroll
            for (int tap = 0; tap < 3; ++tap) {
                #pragma unroll
                for (int kb = 0; kb < NKB; ++kb) {
                    bf16x8 bf = *(const bf16x8*)&s_lds[rbase[tt] + tap][kb * 16 + l5 * 8];
                    bf16x8 af = (tap < 2) ? afr[tap][kb]
                              : *(const bf16x8*)&w_lds[2][ct * 32 + l31][kb * 16 + l5 * 8];
                    acc = __builtin_amdgcn_mfma_f32_32x32x16_bf16(af, bf, acc, 0, 0, 0);
                }
            }
            // epilogue: k = tanh(acc + bias); hn += we*k; pack s_{e+1} = h + al*k
            #pragma unroll
            for (int q = 0; q < 4; ++q) {
                int c0 = ct * 32 + l5 * 4 + q * 8;
                f32x4 bias = *(const f32x4*)&cb_lds[c0];
                #pragma unroll
                for (int j = 0; j < 4; ++j) {
                    float x = acc[q * 4 + j] + bias[j];
                    x = fminf(fmaxf(x, -20.0f), 20.0f);
                    float ex = __builtin_amdgcn_exp2f(x * 2.8853900817779268f);
                    float kv = (ex - 1.0f) * __builtin_amdgcn_rcpf(ex + 1.0f);
                    hn[tt][q * 4 + j] += we * kv;
                    if (e < 3) {
                        float sv = tok[tt] ? (h_reg[tt][q * 4 + j] + al * kv) : 0.0f;
                        spack[tt][q][j] = (__bf16)sv;
                    }
                }
            }
        }
        if (e < 3) {
            __syncthreads();   // all reads of s_e complete
            #pragma unroll
            for (int tt = 0; tt < 4; ++tt) {
                #pragma unroll
                for (int q = 0; q < 4; ++q) {
                    int c0 = ct * 32 + l5 * 4 + q * 8;
                    if (c0 + 4 <= SSTR)
                        *(bf16x4*)&s_lds[rbase[tt] + 1][c0] = spack[tt][q];
                }
            }
            __syncthreads();
        }
    }

    // ---- store hnext (valid window r in [HALO, HALO+W_OUT)) ----
    float* ho = hout + (size_t)b * F_CH * T_LEN;
    #pragma unroll
    for (int tt = 0; tt < 4; ++tt) {
        int r = rbase[tt];
        int t = T0 - HALO + r;
        bool rok = (r >= HALO) && (r < HALO + W_OUT) && (t < T_LEN);
        #pragma unroll
        for (int q = 0; q < 4; ++q) {
            int c0 = ct * 32 + l5 * 4 + q * 8;
            if (rok && c0 < F_CH) {
                #pragma unroll
                for (int j = 0; j < 4; ++j)
                    ho[(size_t)(c0 + j) * T_LEN + t] = hn[tt][q * 4 + j];
            }
        }
    }
}

// ------------- final linear: out[b,t,c] = sum_f h[b,f,t]*fw[c,f] + fb[c] -------------
__global__ __launch_bounds__(256) void final_kernel(
    const float* __restrict__ h, const float* __restrict__ fw,
    const float* __restrict__ fb, float* __restrict__ out, int b0)
{
    int bl = blockIdx.y;
    int t  = blockIdx.x * 256 + threadIdx.x;
    const float* hb = h + (size_t)bl * F_CH * T_LEN;
    float acc[C_CLS];
#pragma unroll
    for (int c = 0; c < C_CLS; ++c) acc[c] = fb[c];
    for (int f = 0; f < F_CH; ++f) {
        float hv = hb[(size_t)f * T_LEN + t];
#pragma unroll
        for (int c = 0; c < C_CLS; ++c) acc[c] = fmaf(fw[c * F_CH + f], hv, acc[c]);
    }
    float* ob = out + ((size_t)(b0 + bl) * T_LEN + t) * C_CLS;
#pragma unroll
    for (int c = 0; c < C_CLS; ++c) ob[c] = acc[c];
}

extern "C" void kernel_launch(void* const* d_in, const int* in_sizes, int n_in,
                              void* d_out, int out_size, void* d_ws, size_t ws_size,
                              hipStream_t stream)
{
    const float* x  = (const float*)d_in[0];
    const float* cw = (const float*)d_in[1];
    const float* cb = (const float*)d_in[2];
    const float* fw = (const float*)d_in[3];
    const float* fb = (const float*)d_in[4];
    float* out = (float*)d_out;

    const size_t FT = (size_t)F_CH * T_LEN;

    __bf16* WPB = (__bf16*)d_ws;
    const size_t wpbFloats = 12800;  // 3*96*88 bf16 = 12672 f32-equiv, padded
    float* planes = (float*)d_ws + wpbFloats;

    size_t planeBytes = 2 * FT * sizeof(float);
    size_t avail = ws_size - wpbFloats * sizeof(float);
    int Bc = (int)(avail / planeBytes);
    if (Bc > B_TOT) Bc = B_TOT;
    if (Bc < 1) Bc = 1;

    float* H0 = planes;
    float* H1 = H0 + (size_t)Bc * FT;

    wprep_kernel<<<(3 * 96 * SSTR + 255) / 256, 256, 0, stream>>>(cw, WPB);

    for (int b0 = 0; b0 < B_TOT; b0 += Bc) {
        int bc = (B_TOT - b0 < Bc) ? (B_TOT - b0) : Bc;

        dim3 gT(T_LEN / 32, bc);
        transpose_kernel<<<gT, 256, 0, stream>>>(x, H0, b0);

        float* hcur = H0;
        float* hnxt = H1;
        dim3 gR(NBT, bc);
        for (int st = 0; st < NSTEP; ++st) {
            rk4_step_kernel<<<gR, TPB, 0, stream>>>(hcur, hnxt, WPB, cb);
            float* tmp = hcur; hcur = hnxt; hnxt = tmp;
        }

        dim3 gF(T_LEN / 256, bc);
        final_kernel<<<gF, 256, 0, stream>>>(hcur, fw, fb, out, b0);
    }
}

// Round 5
// 1041.451 us; speedup vs baseline: 9.5024x; 3.4688x over previous
//
#include <hip/hip_runtime.h>
#include <cstdint>
#include <cstddef>

#define F_CH 76
#define T_LEN 4096
#define B_TOT 64
#define C_CLS 15
#define NSTEP 8

// ---- rk4 fused-step kernel geometry ----
#define W_OUT  120           // output t per block (halo 4 each side)
#define HALO   4
#define NBT    35            // ceil(4096/120)
#define NKB    5             // k-blocks of 16 (ci padded to 80)
#define SSTR   88            // s_lds row stride in bf16
#define SROWS  130           // 128 compute rows + 2 halo
#define TPB    768           // 12 waves: (ct 0..2) x (tq 0..3)
#define HP     96            // h global row pitch (floats)

typedef __attribute__((ext_vector_type(8)))  __bf16 bf16x8;
typedef __attribute__((ext_vector_type(4)))  __bf16 bf16x4;
typedef __attribute__((ext_vector_type(16))) float  f32x16;
typedef __attribute__((ext_vector_type(4)))  float  f32x4;

// ---------------- pad-copy: x [B,T,76] -> h [Bc,T,96] (pad cols zero) ----------------
__global__ __launch_bounds__(256) void pad_copy_kernel(
    const float* __restrict__ x, float* __restrict__ h, int b0)
{
    int bl = blockIdx.y;
    int q  = blockIdx.x * 256 + threadIdx.x;      // quad index within batch
    int t  = q / 24, c4 = (q - t * 24) * 4;
    float4 v = {0.f, 0.f, 0.f, 0.f};
    if (c4 < F_CH)
        v = *(const float4*)(x + ((size_t)(b0 + bl) * T_LEN + t) * F_CH + c4);
    *(float4*)(h + ((size_t)bl * T_LEN + t) * HP + c4) = v;
}

// ---- weight prep: cw [76][76][3] f32 -> wpb [3][96][SSTR] bf16 (zero-padded) ----
__global__ __launch_bounds__(256) void wprep_kernel(
    const float* __restrict__ cw, __bf16* __restrict__ wpb)
{
    int idx = blockIdx.x * 256 + threadIdx.x;
    if (idx >= 3 * 96 * SSTR) return;
    int tap = idx / (96 * SSTR);
    int rem = idx - tap * 96 * SSTR;
    int c = rem / SSTR, ci = rem - c * SSTR;
    float v = 0.0f;
    if (c < F_CH && ci < F_CH) v = cw[((size_t)c * F_CH + ci) * 3 + tap];
    wpb[idx] = (__bf16)v;
}

// ---------------- fused RK4 step: hout = h + dt/6 (k1+2k2+2k3+k4) ----------------
__global__ __launch_bounds__(TPB, 3) void rk4_step_kernel(
    const float* __restrict__ hin, float* __restrict__ hout,
    const __bf16* __restrict__ wpb, const float* __restrict__ cb)
{
    __shared__ __bf16 s_lds[SROWS][SSTR];
    __shared__ float  cb_lds[96];

    const int b    = blockIdx.y;
    const int T0   = blockIdx.x * W_OUT;
    const int tid  = threadIdx.x;
    const int lane = tid & 63;
    const int l31  = lane & 31;
    const int l5   = lane >> 5;          // 0..1
    const int wv   = tid >> 6;           // 0..11
    const int ct   = wv >> 2;            // c-tile 0..2
    const int tq   = wv & 3;             // t-tile 0..3

    const int  rb  = tq * 32 + l31;      // row base 0..127
    const int  t   = T0 - HALO + rb;
    const bool tok = (t >= 0 && t < T_LEN);

    // zero the 2 halo rows (44 dwords each); stage bias
    if (tid < 44) {
        ((uint32_t*)&s_lds[0][0])[tid]         = 0u;
        ((uint32_t*)&s_lds[SROWS - 1][0])[tid] = 0u;
    }
    if (tid < 96) cb_lds[tid] = (tid < F_CH) ? cb[tid] : 0.0f;

    // ---- load h (f32, vectorized); init hn ----
    float h_reg[16], hn[16];
    const float* hb = hin + (size_t)b * T_LEN * HP;
    #pragma unroll
    for (int q = 0; q < 4; ++q) {
        int c0 = ct * 32 + l5 * 4 + q * 8;
        float4 v = {0.f, 0.f, 0.f, 0.f};
        if (tok) v = *(const float4*)(hb + (size_t)t * HP + c0);
        h_reg[q * 4 + 0] = v.x; h_reg[q * 4 + 1] = v.y;
        h_reg[q * 4 + 2] = v.z; h_reg[q * 4 + 3] = v.w;
        hn[q * 4 + 0] = v.x; hn[q * 4 + 1] = v.y;
        hn[q * 4 + 2] = v.z; hn[q * 4 + 3] = v.w;
    }

    // ---- A fragments: all 3 taps x 5 k-blocks, registers, from global (L2) ----
    bf16x8 afr[3][NKB];
    #pragma unroll
    for (int tap = 0; tap < 3; ++tap)
        #pragma unroll
        for (int kb = 0; kb < NKB; ++kb)
            afr[tap][kb] = *(const bf16x8*)&wpb[((size_t)tap * 96 + ct * 32 + l31) * SSTR
                                                + kb * 16 + l5 * 8];

    // ---- write s1 = bf16(h) ----
    #pragma unroll
    for (int q = 0; q < 4; ++q) {
        int c0 = ct * 32 + l5 * 4 + q * 8;
        if (c0 + 4 <= SSTR) {
            bf16x4 p;
            #pragma unroll
            for (int j = 0; j < 4; ++j) p[j] = (__bf16)h_reg[q * 4 + j];
            *(bf16x4*)&s_lds[rb + 1][c0] = p;
        }
    }
    __syncthreads();

    const float dt = 0.125f;
    bf16x4 spack[4];

    #pragma unroll 1
    for (int e = 0; e < 4; ++e) {
        const float we = (e == 0 || e == 3) ? dt / 6.0f : dt / 3.0f;
        const float al = (e == 2) ? dt : 0.5f * dt;

        f32x16 acc = {};
        #pragma unroll
        for (int tap = 0; tap < 3; ++tap) {
            #pragma unroll
            for (int kb = 0; kb < NKB; ++kb) {
                bf16x8 bf = *(const bf16x8*)&s_lds[rb + tap][kb * 16 + l5 * 8];
                acc = __builtin_amdgcn_mfma_f32_32x32x16_bf16(afr[tap][kb], bf, acc, 0, 0, 0);
            }
        }

        // epilogue: k = tanh(acc + bias); hn += we*k; pack s_{e+1} = h + al*k
        #pragma unroll
        for (int q = 0; q < 4; ++q) {
            int c0 = ct * 32 + l5 * 4 + q * 8;
            f32x4 bias = *(const f32x4*)&cb_lds[c0];
            #pragma unroll
            for (int j = 0; j < 4; ++j) {
                float x = acc[q * 4 + j] + bias[j];
                x = fminf(fmaxf(x, -20.0f), 20.0f);
                float ex = __builtin_amdgcn_exp2f(x * 2.8853900817779268f);
                float kv = (ex - 1.0f) * __builtin_amdgcn_rcpf(ex + 1.0f);
                hn[q * 4 + j] += we * kv;
                if (e < 3) {
                    float sv = tok ? (h_reg[q * 4 + j] + al * kv) : 0.0f;
                    spack[q][j] = (__bf16)sv;
                }
            }
        }

        if (e < 3) {
            __syncthreads();   // all reads of s_e complete
            #pragma unroll
            for (int q = 0; q < 4; ++q) {
                int c0 = ct * 32 + l5 * 4 + q * 8;
                if (c0 + 4 <= SSTR)
                    *(bf16x4*)&s_lds[rb + 1][c0] = spack[q];
            }
            __syncthreads();   // writes complete
        }
    }

    // ---- store hnext (valid r in [HALO, HALO+W_OUT)) ----
    if (rb >= HALO && rb < HALO + W_OUT && t < T_LEN) {
        float* ho = hout + ((size_t)b * T_LEN + t) * HP;
        #pragma unroll
        for (int q = 0; q < 4; ++q) {
            int c0 = ct * 32 + l5 * 4 + q * 8;
            float4 v;
            v.x = hn[q * 4 + 0]; v.y = hn[q * 4 + 1];
            v.z = hn[q * 4 + 2]; v.w = hn[q * 4 + 3];
            *(float4*)(ho + c0) = v;
        }
    }
}

// ------------- final linear: out[b,t,c] = sum_f h[t][f]*fw[c,f] + fb[c] -------------
__global__ __launch_bounds__(256) void final_kernel(
    const float* __restrict__ h, const float* __restrict__ fw,
    const float* __restrict__ fb, float* __restrict__ out, int b0)
{
    int bl = blockIdx.y;
    int t  = blockIdx.x * 256 + threadIdx.x;
    const float* hr = h + ((size_t)bl * T_LEN + t) * HP;
    float acc[C_CLS];
#pragma unroll
    for (int c = 0; c < C_CLS; ++c) acc[c] = fb[c];
#pragma unroll
    for (int qf = 0; qf < 19; ++qf) {
        float4 v = *(const float4*)(hr + qf * 4);
#pragma unroll
        for (int c = 0; c < C_CLS; ++c) {
            const float* w = fw + c * F_CH + qf * 4;
            acc[c] = fmaf(w[0], v.x, acc[c]);
            acc[c] = fmaf(w[1], v.y, acc[c]);
            acc[c] = fmaf(w[2], v.z, acc[c]);
            acc[c] = fmaf(w[3], v.w, acc[c]);
        }
    }
    float* ob = out + ((size_t)(b0 + bl) * T_LEN + t) * C_CLS;
#pragma unroll
    for (int c = 0; c < C_CLS; ++c) ob[c] = acc[c];
}

extern "C" void kernel_launch(void* const* d_in, const int* in_sizes, int n_in,
                              void* d_out, int out_size, void* d_ws, size_t ws_size,
                              hipStream_t stream)
{
    const float* x  = (const float*)d_in[0];
    const float* cw = (const float*)d_in[1];
    const float* cb = (const float*)d_in[2];
    const float* fw = (const float*)d_in[3];
    const float* fb = (const float*)d_in[4];
    float* out = (float*)d_out;

    const size_t FT = (size_t)T_LEN * HP;            // floats per batch plane

    __bf16* WPB = (__bf16*)d_ws;
    const size_t wpbFloats = 12800;                  // 3*96*88 bf16, padded
    float* planes = (float*)d_ws + wpbFloats;

    size_t planeBytes = 2 * FT * sizeof(float);
    size_t avail = ws_size - wpbFloats * sizeof(float);
    int Bc = (int)(avail / planeBytes);
    if (Bc > B_TOT) Bc = B_TOT;
    if (Bc < 1) Bc = 1;

    float* H0 = planes;
    float* H1 = H0 + (size_t)Bc * FT;

    wprep_kernel<<<(3 * 96 * SSTR + 255) / 256, 256, 0, stream>>>(cw, WPB);

    for (int b0 = 0; b0 < B_TOT; b0 += Bc) {
        int bc = (B_TOT - b0 < Bc) ? (B_TOT - b0) : Bc;

        dim3 gP(T_LEN * 24 / 256, bc);
        pad_copy_kernel<<<gP, 256, 0, stream>>>(x, H0, b0);

        float* hcur = H0;
        float* hnxt = H1;
        dim3 gR(NBT, bc);
        for (int st = 0; st < NSTEP; ++st) {
            rk4_step_kernel<<<gR, TPB, 0, stream>>>(hcur, hnxt, WPB, cb);
            float* tmp = hcur; hcur = hnxt; hnxt = tmp;
        }

        dim3 gF(T_LEN / 256, bc);
        final_kernel<<<gF, 256, 0, stream>>>(hcur, fw, fb, out, b0);
    }
}